// Round 9
// baseline (186.026 us; speedup 1.0000x reference)
//
#include <hip/hip_runtime.h>

// TriangleAttentionStartingNode: B=1, N=256, d=128, h=4, c=32.
// Round 14 = round 13 with the attn C-operand fold REVERTED (r8 counters:
// it doubled attn VGPR 60->120, occupancy 35->20%, dur 45.5->68.8us - the
// tri/bias staging lived across the MFMA and serialized its issue). The HW
// __bf16 f2bf convert is KEPT (proj/outproj improved ~15us in r8).
// attn inner loop is back to the round-12 shape: zero-C MFMA -> add bias
// after -> exp2. Everything else identical to round 13.

#define NDIM 256
#define HDIM 4
#define QK_SCALE 0.17677669529663687f  // 32^-0.5
#define LOG2E    1.4426950408889634f

typedef unsigned short u16;
typedef unsigned int u32;
typedef __attribute__((ext_vector_type(8))) short bf16x8;
typedef __attribute__((ext_vector_type(4))) float f32x4;

__device__ __forceinline__ float bf2f_lo(u32 u){ union {u32 i; float f;} v; v.i = u<<16; return v.f; }
__device__ __forceinline__ float bf2f_hi(u32 u){ union {u32 i; float f;} v; v.i = u & 0xffff0000u; return v.f; }
__device__ __forceinline__ float bf2f(u16 u){ union {u32 i; float f;} v; v.i = ((u32)u)<<16; return v.f; }
__device__ __forceinline__ u16 f2bf(float f){
    __bf16 h = (__bf16)f;                       // HW RNE convert
    union { __bf16 b; u16 u; } v; v.b = h; return v.u;
}
__device__ __forceinline__ u32 pack2(float a, float b){ return ((u32)f2bf(a)) | (((u32)f2bf(b))<<16); }
// 5-bit rotate-left by 2 (sigma^2): orig c -> final packed hc position
__device__ __forceinline__ int sig2(int c){ return ((c&7)<<2) | (c>>3); }

template<bool BF16> __device__ __forceinline__ float ld1(const void* p, long i){
    if (BF16) return bf2f(((const u16*)p)[i]);
    return ((const float*)p)[i];
}
template<bool BF16> __device__ __forceinline__ float2 ld2f(const void* p, long pair){
    if (BF16){ u32 u = ((const u32*)p)[pair]; return make_float2(bf2f_lo(u), bf2f_hi(u)); }
    return ((const float2*)p)[pair];
}
template<bool BF16> __device__ __forceinline__ void st1(void* p, long i, float v){
    if (BF16) ((u16*)p)[i] = f2bf(v);
    else      ((float*)p)[i] = v;
}
template<bool BF16> __device__ __forceinline__ void load8f(const void* p, long idx, float* f){
    if (BF16){
        uint4 u = *(const uint4*)((const u16*)p + idx);
        f[0]=bf2f_lo(u.x); f[1]=bf2f_hi(u.x); f[2]=bf2f_lo(u.y); f[3]=bf2f_hi(u.y);
        f[4]=bf2f_lo(u.z); f[5]=bf2f_hi(u.z); f[6]=bf2f_lo(u.w); f[7]=bf2f_hi(u.w);
    } else {
        const float4* q = (const float4*)((const float*)p + idx);
        float4 a = q[0], b = q[1];
        f[0]=a.x; f[1]=a.y; f[2]=a.z; f[3]=a.w; f[4]=b.x; f[5]=b.y; f[6]=b.z; f[7]=b.w;
    }
}
__device__ __forceinline__ bf16x8 pack8(const float* f){
    bf16x8 r;
    #pragma unroll
    for (int j = 0; j < 8; j++) r[j] = (short)f2bf(f[j]);
    return r;
}
__device__ __forceinline__ void unpack16(uint4 u, u16* e){
    e[0]=(u16)u.x; e[1]=(u16)(u.x>>16); e[2]=(u16)u.y; e[3]=(u16)(u.y>>16);
    e[4]=(u16)u.z; e[5]=(u16)(u.z>>16); e[6]=(u16)u.w; e[7]=(u16)(u.w>>16);
}
__device__ __forceinline__ bool mask_is_bf16(const void* mask){
    return ((const u32*)mask)[0] == 0x3F803F80u;
}

// ===========================================================================
// prep: one-time weight transpose/convert into workspace.
// ===========================================================================
template<bool BF16>
__device__ __forceinline__ void prep_body(
    const void* wq, const void* wk, const void* wv, const void* wg,
    const void* wb, const void* wo,
    u16* __restrict__ wT4, u16* __restrict__ wbT,
    u16* __restrict__ woP, u16* __restrict__ woL)
{
    int id = blockIdx.x*256 + threadIdx.x;
    int stride = gridDim.x*256;
    const void* Ws[4] = {wq, wk, wv, wg};
    for (int idx = id; idx < 4*16384; idx += stride){
        int m = idx >> 14, r = idx & 16383, n = r >> 7, d = r & 127;
        wT4[idx] = f2bf(ld1<BF16>(Ws[m], (long)d*128 + n));
    }
    for (int idx = id; idx < 2048; idx += stride){
        int n = idx >> 7, d = idx & 127;
        wbT[idx] = (n < 4) ? f2bf(ld1<BF16>(wb, (long)d*4 + n)) : (u16)0;
    }
    for (int idx = id; idx < 16384; idx += stride){
        int dout = idx >> 7, hc = idx & 127;
        int hh = hc >> 5, c = hc & 31;
        float v = ld1<BF16>(wo, (long)hc*128 + dout);
        woL[idx] = f2bf(v);
        woP[dout*128 + hh*32 + sig2(c)] = f2bf(v);
    }
}

__global__ __launch_bounds__(256) void prep_kernel(
    const void* mask, const void* wq, const void* wk, const void* wv,
    const void* wg, const void* wb, const void* wo,
    u16* wT4, u16* wbT, u16* woP, u16* woL)
{
    if (mask_is_bf16(mask)) prep_body<true >(wq,wk,wv,wg,wb,wo,wT4,wbT,woP,woL);
    else                    prep_body<false>(wq,wk,wv,wg,wb,wo,wT4,wbT,woP,woL);
}

// ===========================================================================
// Kernel A: LN(Z) tile + 4 MFMA GEMMs -> qb/kb/vb/gb [i][h][j][c~] + tribT.
//   512 threads, 8 waves; wave w owns rows [w*16, w*16+16). Weights staged
//   into LDS once per block (uint4 copy of prepacked wT4), shared by waves.
// ===========================================================================
template<bool BF16>
__device__ __forceinline__ void proj_body(
    const void* __restrict__ zraw,
    const void* __restrict__ lnw, const void* __restrict__ lnb,
    const u16* __restrict__ wT4, const u16* __restrict__ wbT,
    const void* __restrict__ bg,
    u16* __restrict__ trib,
    u16* __restrict__ qb, u16* __restrict__ kb,
    u16* __restrict__ vb, u16* __restrict__ gb,
    u16* __restrict__ zA, u16* __restrict__ wS, float* __restrict__ fS)
{
    float* muS = fS;       float* rsS = fS + 128;
    float* lnS = fS + 256; float* lbS = fS + 384;
    int t = threadIdx.x, w = t >> 6, L = t & 63, lm = L & 15, lq = L >> 4;
    int pos0 = blockIdx.x * 128;
    int i = pos0 >> 8, j0 = pos0 & 255;

    // phase 1: LN params + raw Z tile -> zA (bf16)
    if (t < 128){ lnS[t] = ld1<BF16>(lnw, t); lbS[t] = ld1<BF16>(lnb, t); }
    if (BF16){
        const uint4* zp = (const uint4*)((const u16*)zraw + (long)pos0*128);
        #pragma unroll
        for (int n = 0; n < 4; n++){
            int g = t + n*512;
            int row = g >> 4, c0 = (g & 15)*8;
            *(uint4*)&zA[row*136 + c0] = zp[g];
        }
    } else {
        const float4* zp = (const float4*)((const float*)zraw + (long)pos0*128);
        #pragma unroll
        for (int n = 0; n < 8; n++){
            int g = t + n*512;
            int row = g >> 5, c0 = (g & 31)*4;
            float4 f = zp[g];
            *(u32*)&zA[row*136 + c0]     = pack2(f.x, f.y);
            *(u32*)&zA[row*136 + c0 + 2] = pack2(f.z, f.w);
        }
    }
    __syncthreads();
    // phase 2: row stats (4 threads/row)
    {
        int row = t >> 2, quarter = t & 3;
        float s = 0.f, ss = 0.f;
        #pragma unroll
        for (int n = 0; n < 4; n++){
            bf16x8 v = *(const bf16x8*)&zA[row*136 + quarter*32 + n*8];
            #pragma unroll
            for (int j = 0; j < 8; j++){ float x = bf2f((u16)v[j]); s += x; ss += x*x; }
        }
        s += __shfl_xor(s, 1); ss += __shfl_xor(ss, 1);
        s += __shfl_xor(s, 2); ss += __shfl_xor(ss, 2);
        if (quarter == 0){
            float mu = s*(1.f/128.f);
            float var = ss*(1.f/128.f) - mu*mu;
            muS[row] = mu; rsS[row] = rsqrtf(var + 1e-5f);
        }
    }
    __syncthreads();
    // phase 3: normalize in place
    #pragma unroll 8
    for (int n = 0; n < 32; n++){
        int e = t + n*512;
        int row = e >> 7, col = e & 127;
        float x = bf2f(zA[row*136 + col]);
        zA[row*136 + col] = f2bf((x - muS[row])*rsS[row]*lnS[col] + lbS[col]);
    }
    __syncthreads();
    f32x4 zero = {0.f,0.f,0.f,0.f};
    // persistent A-frags: wave w's 16 rows (16 VGPRs)
    bf16x8 aA[4];
    #pragma unroll
    for (int ks = 0; ks < 4; ks++)
        aA[ks] = *(const bf16x8*)&zA[(w*16 + lm)*136 + ks*32 + lq*8];
    // phase 4: tri (B from prepacked wbT, L2-hot 4 KB)
    {
        f32x4 a = zero;
        #pragma unroll
        for (int ks = 0; ks < 4; ks++){
            bf16x8 bB = *(const bf16x8*)&wbT[lm*128 + ks*32 + lq*8];
            a = __builtin_amdgcn_mfma_f32_16x16x32_bf16(aA[ks], bB, a, 0, 0, 0);
        }
        if (lm < 4){
            #pragma unroll
            for (int r = 0; r < 4; r++){
                int k = j0 + w*16 + lq*4 + r;
                trib[((long)(lm*NDIM + k))*NDIM + i] = f2bf(a[r]*LOG2E);
            }
        }
    }
    // phase 5: 4 projection GEMMs, weight staged to LDS per matrix
    u16* Os[4] = {qb, kb, vb, gb};
    for (int m = 0; m < 4; m++){
        const u16* Wp = wT4 + m*16384;
        __syncthreads();                       // protect wS from prior reads
        #pragma unroll
        for (int n = 0; n < 4; n++){           // 2048 uint4 = 128 rows x 16 uint4
            int g = t + n*512;
            int row = g >> 4, c0 = (g & 15)*8;
            *(uint4*)&wS[row*136 + c0] = ((const uint4*)Wp)[g];
        }
        __syncthreads();
        f32x4 acc[8];
        #pragma unroll
        for (int n8 = 0; n8 < 8; n8++) acc[n8] = zero;
        #pragma unroll
        for (int ks = 0; ks < 4; ks++){
            bf16x8 bB[8];
            #pragma unroll
            for (int n8 = 0; n8 < 8; n8++)
                bB[n8] = *(const bf16x8*)&wS[(n8*16 + lm)*136 + ks*32 + lq*8];
            #pragma unroll
            for (int n8 = 0; n8 < 8; n8++)
                acc[n8] = __builtin_amdgcn_mfma_f32_16x16x32_bf16(aA[ks], bB[n8], acc[n8], 0, 0, 0);
        }
        u16* outp = Os[m];
        #pragma unroll
        for (int tp = 0; tp < 4; tp++){
            float bg0 = (m == 3) ? ld1<BF16>(bg, tp*32 + lm)      : 0.f;
            float bg1 = (m == 3) ? ld1<BF16>(bg, tp*32 + 16 + lm) : 0.f;
            #pragma unroll
            for (int r = 0; r < 4; r++){
                float v0 = acc[2*tp][r], v1 = acc[2*tp + 1][r];
                if (m == 0){ v0 *= QK_SCALE*LOG2E; v1 *= QK_SCALE*LOG2E; }
                if (m == 3){
                    v0 = 1.f/(1.f + __expf(-(v0 + bg0)));
                    v1 = 1.f/(1.f + __expf(-(v1 + bg1)));
                }
                int row = w*16 + lq*4 + r;
                u32* dst = (u32*)(outp + ((long)(i*HDIM + tp)*NDIM + (j0 + row))*32);
                dst[lm] = pack2(v0, v1);
            }
        }
    }
}

__global__ __launch_bounds__(512, 2) void proj_kernel(
    const void* zraw, const void* mask,
    const void* lnw, const void* lnb,
    const u16* wT4, const u16* wbT, const void* bg,
    u16* trib, u16* qb, u16* kb, u16* vb, u16* gb)
{
    __shared__ u16 zA[128*136];
    __shared__ u16 wS[128*136];
    __shared__ float fS[512];
    if (mask_is_bf16(mask)) proj_body<true >(zraw, lnw, lnb, wT4, wbT, bg, trib, qb, kb, vb, gb, zA, wS, fS);
    else                    proj_body<false>(zraw, lnw, lnb, wT4, wbT, bg, trib, qb, kb, vb, gb, zA, wS, fS);
}

// ===========================================================================
// Kernel B: single-pass flash attention, shift-free exp2 softmax.
//   grid 1024 = i*4 + h; 512 threads (8 waves), each wave owns 32 q rows.
//   Zero-C MFMA; bias added post-MFMA (r12 form - r13's C-fold regressed).
// ===========================================================================
template<bool BF16>
__device__ __forceinline__ void attn_body(
    const void* __restrict__ mask,
    const u16* __restrict__ qb, const u16* __restrict__ kb,
    const u16* __restrict__ vb, const u16* __restrict__ gb,
    const u16* __restrict__ trib, u16* __restrict__ obuf,
    u16* __restrict__ kS, u16* __restrict__ vS, u16* __restrict__ pT,
    float* __restrict__ mrow)
{
    int b = blockIdx.x;
    int i = b >> 2, h = b & 3;
    int t = threadIdx.x, w = t >> 6, L = t & 63, lm = L & 15, lq = L >> 4;
    long base = (long)(i*HDIM + h)*NDIM*32;

    const uint4* kp = (const uint4*)(kb + base);
    const uint4* vp = (const uint4*)(vb + base);
    #pragma unroll
    for (int n = 0; n < 2; n++){
        int g = t + n*512;                    // 1024 uint4 = 256 keys x 32 c~
        int j = g >> 2, c0 = (g & 3)*8;
        *(uint4*)&kS[j*40 + c0] = kp[g];
        int jl = j & 31;
        int jp = (j & ~31) | ((jl & 15) << 1) | (jl >> 4);   // sigma on key
        u16 e[8]; unpack16(vp[g], e);
        #pragma unroll
        for (int q2 = 0; q2 < 8; q2++)
            vS[(jp >> 3)*264 + (c0 + q2)*8 + (jp & 7)] = e[q2];
    }
    if (t < 256) mrow[t] = (1e9f*LOG2E)*(ld1<BF16>(mask, i*NDIM + t) - 1.f);
    int q0 = w*32;
    bf16x8 qA[2];
    #pragma unroll
    for (int Mt = 0; Mt < 2; Mt++)
        qA[Mt] = *(const bf16x8*)(qb + base + (long)(q0 + Mt*16 + lm)*32 + lq*8);

    const u16* trT = trib + (long)h*NDIM*NDIM;   // [k][q], pre-scaled by LOG2E
    uint2 tc0[2], tc1[2];
    #pragma unroll
    for (int Mt = 0; Mt < 2; Mt++){
        tc0[Mt] = *(const uint2*)&trT[((long)(lm))*NDIM + q0 + Mt*16 + lq*4];
        tc1[Mt] = *(const uint2*)&trT[((long)(16 + lm))*NDIM + q0 + Mt*16 + lq*4];
    }
    __syncthreads();

    f32x4 zero = {0.f,0.f,0.f,0.f};
    float lsum[2][4] = {{0.f,0.f,0.f,0.f},{0.f,0.f,0.f,0.f}};
    f32x4 O[2][2];
    O[0][0] = zero; O[0][1] = zero; O[1][0] = zero; O[1][1] = zero;
    u16* myp = pT + w*(32*40);            // per-wave [32 q][40] P buffer

    for (int kt = 0; kt < 8; kt++){
        uint2 tn0[2], tn1[2];
        if (kt < 7){
            #pragma unroll
            for (int Mt = 0; Mt < 2; Mt++){
                tn0[Mt] = *(const uint2*)&trT[((long)((kt+1)*32 + lm))*NDIM + q0 + Mt*16 + lq*4];
                tn1[Mt] = *(const uint2*)&trT[((long)((kt+1)*32 + 16 + lm))*NDIM + q0 + Mt*16 + lq*4];
            }
        } else {
            #pragma unroll
            for (int Mt = 0; Mt < 2; Mt++){ tn0[Mt] = tc0[Mt]; tn1[Mt] = tc1[Mt]; }
        }
        bf16x8 kB0 = *(const bf16x8*)&kS[(kt*32 + lm)*40 + lq*8];
        bf16x8 kB1 = *(const bf16x8*)&kS[(kt*32 + 16 + lm)*40 + lq*8];
        float mb0 = mrow[kt*32 + lm], mb1 = mrow[kt*32 + 16 + lm];
        #pragma unroll
        for (int Mt = 0; Mt < 2; Mt++){
            f32x4 S0 = __builtin_amdgcn_mfma_f32_16x16x32_bf16(qA[Mt], kB0, zero, 0, 0, 0);
            f32x4 S1 = __builtin_amdgcn_mfma_f32_16x16x32_bf16(qA[Mt], kB1, zero, 0, 0, 0);
            float tv0[4] = {bf2f_lo(tc0[Mt].x), bf2f_hi(tc0[Mt].x), bf2f_lo(tc0[Mt].y), bf2f_hi(tc0[Mt].y)};
            float tv1[4] = {bf2f_lo(tc1[Mt].x), bf2f_hi(tc1[Mt].x), bf2f_lo(tc1[Mt].y), bf2f_hi(tc1[Mt].y)};
            #pragma unroll
            for (int r = 0; r < 4; r++){
                float x0 = S0[r] + mb0 + tv0[r];
                float x1 = S1[r] + mb1 + tv1[r];
                float p0 = __builtin_amdgcn_exp2f(fminf(x0, 80.f));
                float p1 = __builtin_amdgcn_exp2f(fminf(x1, 80.f));
                lsum[Mt][r] += p0 + p1;
                *(u32*)&myp[(Mt*16 + lq*4 + r)*40 + 2*lm] = pack2(p0, p1);
            }
        }
        #pragma unroll
        for (int Mt = 0; Mt < 2; Mt++){
            bf16x8 pA = *(const bf16x8*)&myp[(Mt*16 + lm)*40 + lq*8];
            bf16x8 vB0 = *(const bf16x8*)&vS[(kt*4 + lq)*264 + lm*8];
            bf16x8 vB1 = *(const bf16x8*)&vS[(kt*4 + lq)*264 + (16 + lm)*8];
            O[Mt][0] = __builtin_amdgcn_mfma_f32_16x16x32_bf16(pA, vB0, O[Mt][0], 0, 0, 0);
            O[Mt][1] = __builtin_amdgcn_mfma_f32_16x16x32_bf16(pA, vB1, O[Mt][1], 0, 0, 0);
        }
        #pragma unroll
        for (int Mt = 0; Mt < 2; Mt++){ tc0[Mt] = tn0[Mt]; tc1[Mt] = tn1[Mt]; }
    }
    #pragma unroll
    for (int Mt = 0; Mt < 2; Mt++)
        #pragma unroll
        for (int r = 0; r < 4; r++){
            float l = lsum[Mt][r];
            #pragma unroll
            for (int off = 1; off <= 8; off <<= 1) l += __shfl_xor(l, off);
            lsum[Mt][r] = l;
        }
    #pragma unroll
    for (int Mt = 0; Mt < 2; Mt++)
        #pragma unroll
        for (int r = 0; r < 4; r++){
            float inv = 1.f/lsum[Mt][r];
            int q = q0 + Mt*16 + lq*4 + r;
            float g0 = bf2f(gb[base + (long)q*32 + lm]);
            float g1 = bf2f(gb[base + (long)q*32 + 16 + lm]);
            u32* dst = (u32*)(obuf + (long)(i*NDIM + q)*128 + h*32);
            dst[lm] = pack2(O[Mt][0][r]*inv*g0, O[Mt][1][r]*inv*g1);
        }
}

__global__ __launch_bounds__(512, 2) void attn_kernel(
    const void* mask, const u16* qb, const u16* kb,
    const u16* vb, const u16* gb, const u16* trib, u16* obuf)
{
    __shared__ u16 kS[256*40];     // 20.0 KB
    __shared__ u16 vS[32*264];     // 16.5 KB
    __shared__ u16 pT[8*32*40];    // 20.0 KB per-wave P buffers
    __shared__ float mrow[256];
    if (mask_is_bf16(mask)) attn_body<true >(mask, qb, kb, vb, gb, trib, obuf, kS, vS, pT, mrow);
    else                    attn_body<false>(mask, qb, kb, vb, gb, trib, obuf, kS, vS, pT, mrow);
}

// ===========================================================================
// Kernel C: output projection + bias + residual. grid 512, 512 threads.
//   Weight staged to LDS once (shared); wS reused as oT for the epilogue.
// ===========================================================================
template<bool BF16>
__device__ __forceinline__ void outproj_body(
    const u16* __restrict__ obuf, const u16* __restrict__ woT,
    const void* __restrict__ obias, const void* __restrict__ zraw,
    void* __restrict__ out,
    u16* __restrict__ wS, float* __restrict__ obS)
{
    int t = threadIdx.x, w = t >> 6, L = t & 63;
    int lm = L & 15, lq = L >> 4;
    if (t < 128) obS[t] = ld1<BF16>(obias, t);
    // stage woT into LDS (uint4 copy): 2048 uint4 = 128 rows x 16 uint4
    #pragma unroll
    for (int n = 0; n < 4; n++){
        int g = t + n*512;
        int row = g >> 4, c0 = (g & 15)*8;
        *(uint4*)&wS[row*136 + c0] = ((const uint4*)woT)[g];
    }
    int pos0 = blockIdx.x*128;
    int r0 = w*16;
    f32x4 zero = {0.f,0.f,0.f,0.f};
    bf16x8 aA[4];
    #pragma unroll
    for (int ks = 0; ks < 4; ks++)
        aA[ks] = *(const bf16x8*)&obuf[((long)(pos0 + r0 + lm))*128 + ks*32 + lq*8];
    __syncthreads();
    f32x4 acc[8];
    #pragma unroll
    for (int n8 = 0; n8 < 8; n8++) acc[n8] = zero;
    #pragma unroll
    for (int ks = 0; ks < 4; ks++){
        bf16x8 bB[8];
        #pragma unroll
        for (int n8 = 0; n8 < 8; n8++)
            bB[n8] = *(const bf16x8*)&wS[(n8*16 + lm)*136 + ks*32 + lq*8];
        #pragma unroll
        for (int n8 = 0; n8 < 8; n8++)
            acc[n8] = __builtin_amdgcn_mfma_f32_16x16x32_bf16(aA[ks], bB[n8], acc[n8], 0, 0, 0);
    }
    __syncthreads();   // all wS B-frag reads done -> reuse as oT
    u16* oT = wS;
    #pragma unroll
    for (int n8 = 0; n8 < 8; n8++)
        #pragma unroll
        for (int r = 0; r < 4; r++)
            oT[(r0 + lq*4 + r)*136 + n8*16 + lm] = f2bf(acc[n8][r]);
    __syncthreads();
    if (BF16){
        const uint4* zp = (const uint4*)((const u16*)zraw + (long)pos0*128);
        uint4* op = (uint4*)((u16*)out + (long)pos0*128);
        #pragma unroll
        for (int n = 0; n < 4; n++){
            int g = t + n*512;
            int row = g >> 4, c0 = (g & 15)*8;
            uint4 ov = *(const uint4*)&oT[row*136 + c0];
            uint4 zv = zp[g];
            u16 oe[8], ze[8]; unpack16(ov, oe); unpack16(zv, ze);
            float v[8];
            #pragma unroll
            for (int j = 0; j < 8; j++) v[j] = bf2f(oe[j]) + obS[c0 + j] + bf2f(ze[j]);
            uint4 res;
            res.x = pack2(v[0], v[1]); res.y = pack2(v[2], v[3]);
            res.z = pack2(v[4], v[5]); res.w = pack2(v[6], v[7]);
            op[g] = res;
        }
    } else {
        const float4* zp = (const float4*)((const float*)zraw + (long)pos0*128);
        float4* op = (float4*)((float*)out + (long)pos0*128);
        #pragma unroll
        for (int n = 0; n < 4; n++){
            int g = t + n*512;
            int row = g >> 4, c0 = (g & 15)*8;
            uint4 ov = *(const uint4*)&oT[row*136 + c0];
            u16 oe[8]; unpack16(ov, oe);
            float4 z0 = zp[2*g], z1 = zp[2*g + 1];
            float4 r0v, r1v;
            r0v.x = bf2f(oe[0]) + obS[c0+0] + z0.x;
            r0v.y = bf2f(oe[1]) + obS[c0+1] + z0.y;
            r0v.z = bf2f(oe[2]) + obS[c0+2] + z0.z;
            r0v.w = bf2f(oe[3]) + obS[c0+3] + z0.w;
            r1v.x = bf2f(oe[4]) + obS[c0+4] + z1.x;
            r1v.y = bf2f(oe[5]) + obS[c0+5] + z1.y;
            r1v.z = bf2f(oe[6]) + obS[c0+6] + z1.z;
            r1v.w = bf2f(oe[7]) + obS[c0+7] + z1.w;
            op[2*g] = r0v; op[2*g + 1] = r1v;
        }
    }
}

__global__ __launch_bounds__(512, 2) void outproj_kernel(
    const void* mask, const u16* obuf, const u16* woT,
    const void* obias, const void* zraw, void* out)
{
    __shared__ u16 wS[128*136];
    __shared__ float obS[128];
    if (mask_is_bf16(mask)) outproj_body<true >(obuf, woT, obias, zraw, out, wS, obS);
    else                    outproj_body<false>(obuf, woT, obias, zraw, out, wS, obS);
}

// ===========================================================================
// FALLBACK PATH (round-4, proven at ws >= 17.8 MB) — unchanged kernels
// ===========================================================================
template<bool BF16>
__global__ __launch_bounds__(256) void ln_tri_kernel(
    const void* __restrict__ zraw, const void* __restrict__ mask,
    const void* __restrict__ lnw, const void* __restrict__ lnb,
    const void* __restrict__ wb, u16* __restrict__ trib)
{
    if (mask_is_bf16(mask) != BF16) return;
    int wave = threadIdx.x >> 6;
    int lane = threadIdx.x & 63;
    int pos = blockIdx.x * 4 + wave;
    float2 f = ld2f<BF16>(zraw, (long)pos*64 + lane);
    float x0 = f.x, x1 = f.y;
    float s = x0 + x1, ss = x0*x0 + x1*x1;
    #pragma unroll
    for (int off = 32; off; off >>= 1){ s += __shfl_xor(s, off); ss += __shfl_xor(ss, off); }
    float mean = s * (1.0f/128.0f);
    float var  = ss * (1.0f/128.0f) - mean*mean;
    float rstd = rsqrtf(var + 1e-5f);
    int d0 = lane*2;
    float y0 = (x0 - mean)*rstd*ld1<BF16>(lnw, d0)   + ld1<BF16>(lnb, d0);
    float y1 = (x1 - mean)*rstd*ld1<BF16>(lnw, d0+1) + ld1<BF16>(lnb, d0+1);
    int i = pos >> 8, j = pos & 255;
    #pragma unroll
    for (int hh = 0; hh < 4; hh++){
        float tp = y0*ld1<BF16>(wb, d0*4 + hh) + y1*ld1<BF16>(wb, (d0+1)*4 + hh);
        #pragma unroll
        for (int off = 32; off; off >>= 1) tp += __shfl_xor(tp, off);
        if (lane == 0) trib[((long)(hh*NDIM + i))*NDIM + j] = f2bf(tp);
    }
}

template<bool BF16>
__global__ __launch_bounds__(256, 2) void attn_mfma_kernel(
    const void* __restrict__ zraw, const void* __restrict__ mask,
    const void* __restrict__ lnw, const void* __restrict__ lnb,
    const void* __restrict__ wq, const void* __restrict__ wk,
    const void* __restrict__ wv, const void* __restrict__ wg,
    const void* __restrict__ bg, const u16* __restrict__ trib,
    u16* __restrict__ obuf)
{
    if (mask_is_bf16(mask) != BF16) return;
    __shared__ u16 wT[32*136];
    __shared__ u16 kS[256*40];
    __shared__ u16 vT[32*264];
    __shared__ u16 pT[4*64*40];
    __shared__ float mrow[256];
    __shared__ float lnS[128], lbS[128];

    int i = blockIdx.x >> 2, h = blockIdx.x & 3;
    int t = threadIdx.x, w = t >> 6, L = t & 63;
    int lm = L & 15, lq = L >> 4;
    mrow[t] = 1e9f*(ld1<BF16>(mask, i*NDIM + t) - 1.0f);
    if (t < 128) lnS[t] = ld1<BF16>(lnw, t);
    else         lbS[t-128] = ld1<BF16>(lnb, t-128);
    __syncthreads();

    int q0 = w*64;
    float zf[4][4][8];
    float s[4] = {0,0,0,0}, ss[4] = {0,0,0,0};
    #pragma unroll
    for (int Mt = 0; Mt < 4; Mt++){
        long row = (long)(i*NDIM + q0 + Mt*16 + lm);
        #pragma unroll
        for (int ks = 0; ks < 4; ks++){
            load8f<BF16>(zraw, row*128 + ks*32 + lq*8, zf[Mt][ks]);
            #pragma unroll
            for (int j = 0; j < 8; j++){ float x = zf[Mt][ks][j]; s[Mt] += x; ss[Mt] += x*x; }
        }
    }
    #pragma unroll
    for (int Mt = 0; Mt < 4; Mt++){
        s[Mt]  += __shfl_xor(s[Mt], 16);  s[Mt]  += __shfl_xor(s[Mt], 32);
        ss[Mt] += __shfl_xor(ss[Mt], 16); ss[Mt] += __shfl_xor(ss[Mt], 32);
    }
    bf16x8 zA[4][4];
    #pragma unroll
    for (int Mt = 0; Mt < 4; Mt++){
        float mean = s[Mt]*(1.f/128.f);
        float var  = ss[Mt]*(1.f/128.f) - mean*mean;
        float rstd = rsqrtf(var + 1e-5f);
        #pragma unroll
        for (int ks = 0; ks < 4; ks++){
            float tmp[8];
            #pragma unroll
            for (int j = 0; j < 8; j++){
                int col = ks*32 + lq*8 + j;
                tmp[j] = (zf[Mt][ks][j] - mean)*rstd*lnS[col] + lbS[col];
            }
            zA[Mt][ks] = pack8(tmp);
        }
    }
    u16* myp = pT + w*2560;
    f32x4 zero = {0.f, 0.f, 0.f, 0.f};
    auto stageW = [&](const void* W){
        for (int idx = t; idx < 4096; idx += 256){
            int c = idx >> 7, d = idx & 127;
            wT[c*136 + d] = f2bf(ld1<BF16>(W, (long)(d*4 + h)*32 + c));
        }
    };
    auto projA = [&](f32x4 (&acc)[4][2]){
        bf16x8 bB[2][4];
        #pragma unroll
        for (int Nt = 0; Nt < 2; Nt++)
            #pragma unroll
            for (int ks = 0; ks < 4; ks++)
                bB[Nt][ks] = *(const bf16x8*)&wT[(Nt*16 + lm)*136 + ks*32 + lq*8];
        #pragma unroll
        for (int Mt = 0; Mt < 4; Mt++)
            #pragma unroll
            for (int Nt = 0; Nt < 2; Nt++){
                f32x4 a = zero;
                #pragma unroll
                for (int ks = 0; ks < 4; ks++)
                    a = __builtin_amdgcn_mfma_f32_16x16x32_bf16(zA[Mt][ks], bB[Nt][ks], a, 0, 0, 0);
                acc[Mt][Nt] = a;
            }
    };
    f32x4 acc[4][2];
    stageW(wq); __syncthreads();
    projA(acc);
    #pragma unroll
    for (int Mt = 0; Mt < 4; Mt++)
        #pragma unroll
        for (int Nt = 0; Nt < 2; Nt++)
            #pragma unroll
            for (int r = 0; r < 4; r++)
                myp[(Mt*16 + lq*4 + r)*40 + Nt*16 + lm] = f2bf(acc[Mt][Nt][r]*QK_SCALE);
    bf16x8 qA[4];
    #pragma unroll
    for (int Mt = 0; Mt < 4; Mt++)
        qA[Mt] = *(const bf16x8*)&myp[(Mt*16 + lm)*40 + lq*8];
    __syncthreads();
    stageW(wk); __syncthreads();
    projA(acc);
    #pragma unroll
    for (int Mt = 0; Mt < 4; Mt++)
        #pragma unroll
        for (int Nt = 0; Nt < 2; Nt++)
            #pragma unroll
            for (int r = 0; r < 4; r++)
                kS[(q0 + Mt*16 + lq*4 + r)*40 + Nt*16 + lm] = f2bf(acc[Mt][Nt][r]);
    __syncthreads();
    stageW(wv); __syncthreads();
    projA(acc);
    #pragma unroll
    for (int Mt = 0; Mt < 4; Mt++)
        #pragma unroll
        for (int Nt = 0; Nt < 2; Nt++)
            #pragma unroll
            for (int r = 0; r < 4; r++)
                vT[(Nt*16 + lm)*264 + q0 + Mt*16 + lq*4 + r] = f2bf(acc[Mt][Nt][r]);
    __syncthreads();
    stageW(wg); __syncthreads();
    f32x4 gv[4][2];
    projA(gv);
    float bgv0 = ld1<BF16>(bg, h*32 + lm), bgv1 = ld1<BF16>(bg, h*32 + 16 + lm);
    #pragma unroll
    for (int Mt = 0; Mt < 4; Mt++)
        #pragma unroll
        for (int r = 0; r < 4; r++){
            gv[Mt][0][r] = 1.f/(1.f + __expf(-(gv[Mt][0][r] + bgv0)));
            gv[Mt][1][r] = 1.f/(1.f + __expf(-(gv[Mt][1][r] + bgv1)));
        }
    __syncthreads();
    float mS[4][4], lS[4][4];
    f32x4 O[4][2];
    #pragma unroll
    for (int Mt = 0; Mt < 4; Mt++){
        #pragma unroll
        for (int r = 0; r < 4; r++){ mS[Mt][r] = -3e38f; lS[Mt][r] = 0.f; }
        O[Mt][0] = zero; O[Mt][1] = zero;
    }
    const u16* trb = trib + ((long)(h*NDIM + q0))*NDIM;
    for (int kt = 0; kt < 8; kt++){
        bf16x8 kB0 = *(const bf16x8*)&kS[(kt*32 + lm)*40 + lq*8];
        bf16x8 kB1 = *(const bf16x8*)&kS[(kt*32 + 16 + lm)*40 + lq*8];
        f32x4 S[4][2];
        #pragma unroll
        for (int Mt = 0; Mt < 4; Mt++){
            S[Mt][0] = __builtin_amdgcn_mfma_f32_16x16x32_bf16(qA[Mt], kB0, zero, 0, 0, 0);
            S[Mt][1] = __builtin_amdgcn_mfma_f32_16x16x32_bf16(qA[Mt], kB1, zero, 0, 0, 0);
        }
        int k0 = kt*32 + lm;
        float mb0 = mrow[k0], mb1 = mrow[k0 + 16];
        #pragma unroll
        for (int Mt = 0; Mt < 4; Mt++){
            #pragma unroll
            for (int r = 0; r < 4; r++){
                int qrow = Mt*16 + lq*4 + r;
                float x0 = S[Mt][0][r] + mb0 + bf2f(trb[(long)qrow*NDIM + k0]);
                float x1 = S[Mt][1][r] + mb1 + bf2f(trb[(long)qrow*NDIM + k0 + 16]);
                float mx = fmaxf(x0, x1);
                #pragma unroll
                for (int off = 1; off <= 8; off <<= 1) mx = fmaxf(mx, __shfl_xor(mx, off));
                float mnew = fmaxf(mS[Mt][r], mx);
                float al = __expf(mS[Mt][r] - mnew);
                float p0 = __expf(x0 - mnew), p1 = __expf(x1 - mnew);
                float rs = p0 + p1;
                #pragma unroll
                for (int off = 1; off <= 8; off <<= 1) rs += __shfl_xor(rs, off);
                lS[Mt][r] = lS[Mt][r]*al + rs;
                mS[Mt][r] = mnew;
                O[Mt][0][r] *= al; O[Mt][1][r] *= al;
                myp[qrow*40 + lm]      = f2bf(p0);
                myp[qrow*40 + 16 + lm] = f2bf(p1);
            }
        }
        bf16x8 vB0 = *(const bf16x8*)&vT[lm*264 + kt*32 + lq*8];
        bf16x8 vB1 = *(const bf16x8*)&vT[(16 + lm)*264 + kt*32 + lq*8];
        #pragma unroll
        for (int Mt = 0; Mt < 4; Mt++){
            bf16x8 pA = *(const bf16x8*)&myp[(Mt*16 + lm)*40 + lq*8];
            O[Mt][0] = __builtin_amdgcn_mfma_f32_16x16x32_bf16(pA, vB0, O[Mt][0], 0, 0, 0);
            O[Mt][1] = __builtin_amdgcn_mfma_f32_16x16x32_bf16(pA, vB1, O[Mt][1], 0, 0, 0);
        }
    }
    #pragma unroll
    for (int Mt = 0; Mt < 4; Mt++)
        #pragma unroll
        for (int r = 0; r < 4; r++){
            float inv = 1.0f/lS[Mt][r];
            int q = q0 + Mt*16 + lq*4 + r;
            long base = ((long)(i*NDIM + q))*128 + h*32;
            obuf[base + lm]      = f2bf(O[Mt][0][r]*inv*gv[Mt][0][r]);
            obuf[base + 16 + lm] = f2bf(O[Mt][1][r]*inv*gv[Mt][1][r]);
        }
}

// ---------------------------------------------------------------------------
extern "C" void kernel_launch(void* const* d_in, const int* in_sizes, int n_in,
                              void* d_out, int out_size, void* d_ws, size_t ws_size,
                              hipStream_t stream)
{
    const void* zraw = d_in[0];
    const void* mask = d_in[1];
    const void* lnw  = d_in[2];
    const void* lnb  = d_in[3];
    const void* wb   = d_in[4];
    const void* wq   = d_in[5];
    const void* wk   = d_in[6];
    const void* wv   = d_in[7];
    const void* wg   = d_in[8];
    const void* bg   = d_in[9];
    const void* wo   = d_in[10];
    const void* obias= d_in[11];

    const size_t KB = 1024;
    const size_t MB = 1024*1024;
    u16* trib = (u16*)d_ws;                               // 512 KB @ 0
    u16* wT4  = (u16*)((char*)d_ws + 512*KB);             // 128 KB
    u16* woP  = (u16*)((char*)d_ws + 640*KB);             // 32 KB
    u16* woL  = (u16*)((char*)d_ws + 672*KB);             // 32 KB
    u16* wbT  = (u16*)((char*)d_ws + 704*KB);             // 4 KB
    size_t need_big = 81*MB;
    bool big = ws_size >= need_big;

    prep_kernel<<<dim3(128), 256, 0, stream>>>(mask, wq, wk, wv, wg, wb, wo,
                                               wT4, wbT, woP, woL);
    if (big){
        u16* qb   = (u16*)((char*)d_ws + 1*MB);
        u16* kb   = (u16*)((char*)d_ws + 17*MB);
        u16* vb   = (u16*)((char*)d_ws + 33*MB);
        u16* gb   = (u16*)((char*)d_ws + 49*MB);
        u16* obuf = (u16*)((char*)d_ws + 65*MB);
        proj_kernel<<<dim3(512), 512, 0, stream>>>(
            zraw, mask, lnw, lnb, wT4, wbT, bg, trib, qb, kb, vb, gb);
        attn_kernel<<<dim3(1024), 512, 0, stream>>>(mask, qb, kb, vb, gb, trib, obuf);
        outproj_kernel<<<dim3(512), 512, 0, stream>>>(mask, obuf, woP, obias, zraw, d_out);
    } else {
        u16* obuf = (u16*)((char*)d_ws + 1*MB);
        ln_tri_kernel<true ><<<dim3(NDIM*NDIM/4), 256, 0, stream>>>(zraw, mask, lnw, lnb, wb, trib);
        ln_tri_kernel<false><<<dim3(NDIM*NDIM/4), 256, 0, stream>>>(zraw, mask, lnw, lnb, wb, trib);
        attn_mfma_kernel<true ><<<dim3(NDIM*HDIM), 256, 0, stream>>>(
            zraw, mask, lnw, lnb, wq, wk, wv, wg, bg, trib, obuf);
        attn_mfma_kernel<false><<<dim3(NDIM*HDIM), 256, 0, stream>>>(
            zraw, mask, lnw, lnb, wq, wk, wv, wg, bg, trib, obuf);
        outproj_kernel<<<dim3(512), 512, 0, stream>>>(mask, obuf, woL, obias, zraw, d_out);
    }
}

// Round 10
// 175.573 us; speedup vs baseline: 1.0595x; 1.0595x over previous
//
#include <hip/hip_runtime.h>

// TriangleAttentionStartingNode: B=1, N=256, d=128, h=4, c=32.
// Round 15: DUAL f2bf. r9 falsified the C-fold theory: attn (reverted to r12
// source except f2bf) still shows VGPR 120 / occ 19.8% / 68us. The __bf16 HW
// convert is the culprit IN ATTN: v_cvt_pk_bf16_f32 formation makes the
// compiler pipeline the kt loop with many p-pairs live -> 60->120 VGPR ->
// +16 AGPR crosses the 128 bucket -> 2-3 waves/SIMD. In proj/outproj the same
// convert was worth ~15us (no occupancy cliff there).
//  - attn: software RNE f2bf (pack2_sw) at its two store sites -> codegen
//    input byte-identical to the measured-good r12 attn (VGPR 60, 45.5us).
//  - prep/proj/outproj: keep HW __bf16 convert.
// Everything else identical to round 14.

#define NDIM 256
#define HDIM 4
#define QK_SCALE 0.17677669529663687f  // 32^-0.5
#define LOG2E    1.4426950408889634f

typedef unsigned short u16;
typedef unsigned int u32;
typedef __attribute__((ext_vector_type(8))) short bf16x8;
typedef __attribute__((ext_vector_type(4))) float f32x4;

__device__ __forceinline__ float bf2f_lo(u32 u){ union {u32 i; float f;} v; v.i = u<<16; return v.f; }
__device__ __forceinline__ float bf2f_hi(u32 u){ union {u32 i; float f;} v; v.i = u & 0xffff0000u; return v.f; }
__device__ __forceinline__ float bf2f(u16 u){ union {u32 i; float f;} v; v.i = ((u32)u)<<16; return v.f; }
// HW convert (RNE) - used in prep/proj/outproj where it measured faster.
__device__ __forceinline__ u16 f2bf(float f){
    __bf16 h = (__bf16)f;
    union { __bf16 b; u16 u; } v; v.b = h; return v.u;
}
__device__ __forceinline__ u32 pack2(float a, float b){ return ((u32)f2bf(a)) | (((u32)f2bf(b))<<16); }
// Software RNE convert - used in attn stores (keeps VGPR at 60; the HW-cast
// version made the compiler pipeline the kt loop to 120 VGPR, r8/r9 counters).
__device__ __forceinline__ u16 f2bf_sw(float f){
    union {u32 i; float f;} v; v.f = f;
    u32 r = v.i + 0x7fffu + ((v.i>>16)&1u);
    return (u16)(r>>16);
}
__device__ __forceinline__ u32 pack2_sw(float a, float b){ return ((u32)f2bf_sw(a)) | (((u32)f2bf_sw(b))<<16); }
// 5-bit rotate-left by 2 (sigma^2): orig c -> final packed hc position
__device__ __forceinline__ int sig2(int c){ return ((c&7)<<2) | (c>>3); }

template<bool BF16> __device__ __forceinline__ float ld1(const void* p, long i){
    if (BF16) return bf2f(((const u16*)p)[i]);
    return ((const float*)p)[i];
}
template<bool BF16> __device__ __forceinline__ float2 ld2f(const void* p, long pair){
    if (BF16){ u32 u = ((const u32*)p)[pair]; return make_float2(bf2f_lo(u), bf2f_hi(u)); }
    return ((const float2*)p)[pair];
}
template<bool BF16> __device__ __forceinline__ void st1(void* p, long i, float v){
    if (BF16) ((u16*)p)[i] = f2bf(v);
    else      ((float*)p)[i] = v;
}
template<bool BF16> __device__ __forceinline__ void load8f(const void* p, long idx, float* f){
    if (BF16){
        uint4 u = *(const uint4*)((const u16*)p + idx);
        f[0]=bf2f_lo(u.x); f[1]=bf2f_hi(u.x); f[2]=bf2f_lo(u.y); f[3]=bf2f_hi(u.y);
        f[4]=bf2f_lo(u.z); f[5]=bf2f_hi(u.z); f[6]=bf2f_lo(u.w); f[7]=bf2f_hi(u.w);
    } else {
        const float4* q = (const float4*)((const float*)p + idx);
        float4 a = q[0], b = q[1];
        f[0]=a.x; f[1]=a.y; f[2]=a.z; f[3]=a.w; f[4]=b.x; f[5]=b.y; f[6]=b.z; f[7]=b.w;
    }
}
__device__ __forceinline__ bf16x8 pack8(const float* f){
    bf16x8 r;
    #pragma unroll
    for (int j = 0; j < 8; j++) r[j] = (short)f2bf(f[j]);
    return r;
}
__device__ __forceinline__ void unpack16(uint4 u, u16* e){
    e[0]=(u16)u.x; e[1]=(u16)(u.x>>16); e[2]=(u16)u.y; e[3]=(u16)(u.y>>16);
    e[4]=(u16)u.z; e[5]=(u16)(u.z>>16); e[6]=(u16)u.w; e[7]=(u16)(u.w>>16);
}
__device__ __forceinline__ bool mask_is_bf16(const void* mask){
    return ((const u32*)mask)[0] == 0x3F803F80u;
}

// ===========================================================================
// prep: one-time weight transpose/convert into workspace.
// ===========================================================================
template<bool BF16>
__device__ __forceinline__ void prep_body(
    const void* wq, const void* wk, const void* wv, const void* wg,
    const void* wb, const void* wo,
    u16* __restrict__ wT4, u16* __restrict__ wbT,
    u16* __restrict__ woP, u16* __restrict__ woL)
{
    int id = blockIdx.x*256 + threadIdx.x;
    int stride = gridDim.x*256;
    const void* Ws[4] = {wq, wk, wv, wg};
    for (int idx = id; idx < 4*16384; idx += stride){
        int m = idx >> 14, r = idx & 16383, n = r >> 7, d = r & 127;
        wT4[idx] = f2bf(ld1<BF16>(Ws[m], (long)d*128 + n));
    }
    for (int idx = id; idx < 2048; idx += stride){
        int n = idx >> 7, d = idx & 127;
        wbT[idx] = (n < 4) ? f2bf(ld1<BF16>(wb, (long)d*4 + n)) : (u16)0;
    }
    for (int idx = id; idx < 16384; idx += stride){
        int dout = idx >> 7, hc = idx & 127;
        int hh = hc >> 5, c = hc & 31;
        float v = ld1<BF16>(wo, (long)hc*128 + dout);
        woL[idx] = f2bf(v);
        woP[dout*128 + hh*32 + sig2(c)] = f2bf(v);
    }
}

__global__ __launch_bounds__(256) void prep_kernel(
    const void* mask, const void* wq, const void* wk, const void* wv,
    const void* wg, const void* wb, const void* wo,
    u16* wT4, u16* wbT, u16* woP, u16* woL)
{
    if (mask_is_bf16(mask)) prep_body<true >(wq,wk,wv,wg,wb,wo,wT4,wbT,woP,woL);
    else                    prep_body<false>(wq,wk,wv,wg,wb,wo,wT4,wbT,woP,woL);
}

// ===========================================================================
// Kernel A: LN(Z) tile + 4 MFMA GEMMs -> qb/kb/vb/gb [i][h][j][c~] + tribT.
//   512 threads, 8 waves; wave w owns rows [w*16, w*16+16). Weights staged
//   into LDS once per block (uint4 copy of prepacked wT4), shared by waves.
// ===========================================================================
template<bool BF16>
__device__ __forceinline__ void proj_body(
    const void* __restrict__ zraw,
    const void* __restrict__ lnw, const void* __restrict__ lnb,
    const u16* __restrict__ wT4, const u16* __restrict__ wbT,
    const void* __restrict__ bg,
    u16* __restrict__ trib,
    u16* __restrict__ qb, u16* __restrict__ kb,
    u16* __restrict__ vb, u16* __restrict__ gb,
    u16* __restrict__ zA, u16* __restrict__ wS, float* __restrict__ fS)
{
    float* muS = fS;       float* rsS = fS + 128;
    float* lnS = fS + 256; float* lbS = fS + 384;
    int t = threadIdx.x, w = t >> 6, L = t & 63, lm = L & 15, lq = L >> 4;
    int pos0 = blockIdx.x * 128;
    int i = pos0 >> 8, j0 = pos0 & 255;

    // phase 1: LN params + raw Z tile -> zA (bf16)
    if (t < 128){ lnS[t] = ld1<BF16>(lnw, t); lbS[t] = ld1<BF16>(lnb, t); }
    if (BF16){
        const uint4* zp = (const uint4*)((const u16*)zraw + (long)pos0*128);
        #pragma unroll
        for (int n = 0; n < 4; n++){
            int g = t + n*512;
            int row = g >> 4, c0 = (g & 15)*8;
            *(uint4*)&zA[row*136 + c0] = zp[g];
        }
    } else {
        const float4* zp = (const float4*)((const float*)zraw + (long)pos0*128);
        #pragma unroll
        for (int n = 0; n < 8; n++){
            int g = t + n*512;
            int row = g >> 5, c0 = (g & 31)*4;
            float4 f = zp[g];
            *(u32*)&zA[row*136 + c0]     = pack2(f.x, f.y);
            *(u32*)&zA[row*136 + c0 + 2] = pack2(f.z, f.w);
        }
    }
    __syncthreads();
    // phase 2: row stats (4 threads/row)
    {
        int row = t >> 2, quarter = t & 3;
        float s = 0.f, ss = 0.f;
        #pragma unroll
        for (int n = 0; n < 4; n++){
            bf16x8 v = *(const bf16x8*)&zA[row*136 + quarter*32 + n*8];
            #pragma unroll
            for (int j = 0; j < 8; j++){ float x = bf2f((u16)v[j]); s += x; ss += x*x; }
        }
        s += __shfl_xor(s, 1); ss += __shfl_xor(ss, 1);
        s += __shfl_xor(s, 2); ss += __shfl_xor(ss, 2);
        if (quarter == 0){
            float mu = s*(1.f/128.f);
            float var = ss*(1.f/128.f) - mu*mu;
            muS[row] = mu; rsS[row] = rsqrtf(var + 1e-5f);
        }
    }
    __syncthreads();
    // phase 3: normalize in place
    #pragma unroll 8
    for (int n = 0; n < 32; n++){
        int e = t + n*512;
        int row = e >> 7, col = e & 127;
        float x = bf2f(zA[row*136 + col]);
        zA[row*136 + col] = f2bf((x - muS[row])*rsS[row]*lnS[col] + lbS[col]);
    }
    __syncthreads();
    f32x4 zero = {0.f,0.f,0.f,0.f};
    // persistent A-frags: wave w's 16 rows (16 VGPRs)
    bf16x8 aA[4];
    #pragma unroll
    for (int ks = 0; ks < 4; ks++)
        aA[ks] = *(const bf16x8*)&zA[(w*16 + lm)*136 + ks*32 + lq*8];
    // phase 4: tri (B from prepacked wbT, L2-hot 4 KB)
    {
        f32x4 a = zero;
        #pragma unroll
        for (int ks = 0; ks < 4; ks++){
            bf16x8 bB = *(const bf16x8*)&wbT[lm*128 + ks*32 + lq*8];
            a = __builtin_amdgcn_mfma_f32_16x16x32_bf16(aA[ks], bB, a, 0, 0, 0);
        }
        if (lm < 4){
            #pragma unroll
            for (int r = 0; r < 4; r++){
                int k = j0 + w*16 + lq*4 + r;
                trib[((long)(lm*NDIM + k))*NDIM + i] = f2bf(a[r]*LOG2E);
            }
        }
    }
    // phase 5: 4 projection GEMMs, weight staged to LDS per matrix
    u16* Os[4] = {qb, kb, vb, gb};
    for (int m = 0; m < 4; m++){
        const u16* Wp = wT4 + m*16384;
        __syncthreads();                       // protect wS from prior reads
        #pragma unroll
        for (int n = 0; n < 4; n++){           // 2048 uint4 = 128 rows x 16 uint4
            int g = t + n*512;
            int row = g >> 4, c0 = (g & 15)*8;
            *(uint4*)&wS[row*136 + c0] = ((const uint4*)Wp)[g];
        }
        __syncthreads();
        f32x4 acc[8];
        #pragma unroll
        for (int n8 = 0; n8 < 8; n8++) acc[n8] = zero;
        #pragma unroll
        for (int ks = 0; ks < 4; ks++){
            bf16x8 bB[8];
            #pragma unroll
            for (int n8 = 0; n8 < 8; n8++)
                bB[n8] = *(const bf16x8*)&wS[(n8*16 + lm)*136 + ks*32 + lq*8];
            #pragma unroll
            for (int n8 = 0; n8 < 8; n8++)
                acc[n8] = __builtin_amdgcn_mfma_f32_16x16x32_bf16(aA[ks], bB[n8], acc[n8], 0, 0, 0);
        }
        u16* outp = Os[m];
        #pragma unroll
        for (int tp = 0; tp < 4; tp++){
            float bg0 = (m == 3) ? ld1<BF16>(bg, tp*32 + lm)      : 0.f;
            float bg1 = (m == 3) ? ld1<BF16>(bg, tp*32 + 16 + lm) : 0.f;
            #pragma unroll
            for (int r = 0; r < 4; r++){
                float v0 = acc[2*tp][r], v1 = acc[2*tp + 1][r];
                if (m == 0){ v0 *= QK_SCALE*LOG2E; v1 *= QK_SCALE*LOG2E; }
                if (m == 3){
                    v0 = 1.f/(1.f + __expf(-(v0 + bg0)));
                    v1 = 1.f/(1.f + __expf(-(v1 + bg1)));
                }
                int row = w*16 + lq*4 + r;
                u32* dst = (u32*)(outp + ((long)(i*HDIM + tp)*NDIM + (j0 + row))*32);
                dst[lm] = pack2(v0, v1);
            }
        }
    }
}

__global__ __launch_bounds__(512, 2) void proj_kernel(
    const void* zraw, const void* mask,
    const void* lnw, const void* lnb,
    const u16* wT4, const u16* wbT, const void* bg,
    u16* trib, u16* qb, u16* kb, u16* vb, u16* gb)
{
    __shared__ u16 zA[128*136];
    __shared__ u16 wS[128*136];
    __shared__ float fS[512];
    if (mask_is_bf16(mask)) proj_body<true >(zraw, lnw, lnb, wT4, wbT, bg, trib, qb, kb, vb, gb, zA, wS, fS);
    else                    proj_body<false>(zraw, lnw, lnb, wT4, wbT, bg, trib, qb, kb, vb, gb, zA, wS, fS);
}

// ===========================================================================
// Kernel B: single-pass flash attention, shift-free exp2 softmax.
//   grid 1024 = i*4 + h; 512 threads (8 waves), each wave owns 32 q rows.
//   Zero-C MFMA; bias added post-MFMA; SOFTWARE f2bf at stores (r12 codegen).
// ===========================================================================
template<bool BF16>
__device__ __forceinline__ void attn_body(
    const void* __restrict__ mask,
    const u16* __restrict__ qb, const u16* __restrict__ kb,
    const u16* __restrict__ vb, const u16* __restrict__ gb,
    const u16* __restrict__ trib, u16* __restrict__ obuf,
    u16* __restrict__ kS, u16* __restrict__ vS, u16* __restrict__ pT,
    float* __restrict__ mrow)
{
    int b = blockIdx.x;
    int i = b >> 2, h = b & 3;
    int t = threadIdx.x, w = t >> 6, L = t & 63, lm = L & 15, lq = L >> 4;
    long base = (long)(i*HDIM + h)*NDIM*32;

    const uint4* kp = (const uint4*)(kb + base);
    const uint4* vp = (const uint4*)(vb + base);
    #pragma unroll
    for (int n = 0; n < 2; n++){
        int g = t + n*512;                    // 1024 uint4 = 256 keys x 32 c~
        int j = g >> 2, c0 = (g & 3)*8;
        *(uint4*)&kS[j*40 + c0] = kp[g];
        int jl = j & 31;
        int jp = (j & ~31) | ((jl & 15) << 1) | (jl >> 4);   // sigma on key
        u16 e[8]; unpack16(vp[g], e);
        #pragma unroll
        for (int q2 = 0; q2 < 8; q2++)
            vS[(jp >> 3)*264 + (c0 + q2)*8 + (jp & 7)] = e[q2];
    }
    if (t < 256) mrow[t] = (1e9f*LOG2E)*(ld1<BF16>(mask, i*NDIM + t) - 1.f);
    int q0 = w*32;
    bf16x8 qA[2];
    #pragma unroll
    for (int Mt = 0; Mt < 2; Mt++)
        qA[Mt] = *(const bf16x8*)(qb + base + (long)(q0 + Mt*16 + lm)*32 + lq*8);

    const u16* trT = trib + (long)h*NDIM*NDIM;   // [k][q], pre-scaled by LOG2E
    uint2 tc0[2], tc1[2];
    #pragma unroll
    for (int Mt = 0; Mt < 2; Mt++){
        tc0[Mt] = *(const uint2*)&trT[((long)(lm))*NDIM + q0 + Mt*16 + lq*4];
        tc1[Mt] = *(const uint2*)&trT[((long)(16 + lm))*NDIM + q0 + Mt*16 + lq*4];
    }
    __syncthreads();

    f32x4 zero = {0.f,0.f,0.f,0.f};
    float lsum[2][4] = {{0.f,0.f,0.f,0.f},{0.f,0.f,0.f,0.f}};
    f32x4 O[2][2];
    O[0][0] = zero; O[0][1] = zero; O[1][0] = zero; O[1][1] = zero;
    u16* myp = pT + w*(32*40);            // per-wave [32 q][40] P buffer

    for (int kt = 0; kt < 8; kt++){
        uint2 tn0[2], tn1[2];
        if (kt < 7){
            #pragma unroll
            for (int Mt = 0; Mt < 2; Mt++){
                tn0[Mt] = *(const uint2*)&trT[((long)((kt+1)*32 + lm))*NDIM + q0 + Mt*16 + lq*4];
                tn1[Mt] = *(const uint2*)&trT[((long)((kt+1)*32 + 16 + lm))*NDIM + q0 + Mt*16 + lq*4];
            }
        } else {
            #pragma unroll
            for (int Mt = 0; Mt < 2; Mt++){ tn0[Mt] = tc0[Mt]; tn1[Mt] = tc1[Mt]; }
        }
        bf16x8 kB0 = *(const bf16x8*)&kS[(kt*32 + lm)*40 + lq*8];
        bf16x8 kB1 = *(const bf16x8*)&kS[(kt*32 + 16 + lm)*40 + lq*8];
        float mb0 = mrow[kt*32 + lm], mb1 = mrow[kt*32 + 16 + lm];
        #pragma unroll
        for (int Mt = 0; Mt < 2; Mt++){
            f32x4 S0 = __builtin_amdgcn_mfma_f32_16x16x32_bf16(qA[Mt], kB0, zero, 0, 0, 0);
            f32x4 S1 = __builtin_amdgcn_mfma_f32_16x16x32_bf16(qA[Mt], kB1, zero, 0, 0, 0);
            float tv0[4] = {bf2f_lo(tc0[Mt].x), bf2f_hi(tc0[Mt].x), bf2f_lo(tc0[Mt].y), bf2f_hi(tc0[Mt].y)};
            float tv1[4] = {bf2f_lo(tc1[Mt].x), bf2f_hi(tc1[Mt].x), bf2f_lo(tc1[Mt].y), bf2f_hi(tc1[Mt].y)};
            #pragma unroll
            for (int r = 0; r < 4; r++){
                float x0 = S0[r] + mb0 + tv0[r];
                float x1 = S1[r] + mb1 + tv1[r];
                float p0 = __builtin_amdgcn_exp2f(fminf(x0, 80.f));
                float p1 = __builtin_amdgcn_exp2f(fminf(x1, 80.f));
                lsum[Mt][r] += p0 + p1;
                *(u32*)&myp[(Mt*16 + lq*4 + r)*40 + 2*lm] = pack2_sw(p0, p1);
            }
        }
        #pragma unroll
        for (int Mt = 0; Mt < 2; Mt++){
            bf16x8 pA = *(const bf16x8*)&myp[(Mt*16 + lm)*40 + lq*8];
            bf16x8 vB0 = *(const bf16x8*)&vS[(kt*4 + lq)*264 + lm*8];
            bf16x8 vB1 = *(const bf16x8*)&vS[(kt*4 + lq)*264 + (16 + lm)*8];
            O[Mt][0] = __builtin_amdgcn_mfma_f32_16x16x32_bf16(pA, vB0, O[Mt][0], 0, 0, 0);
            O[Mt][1] = __builtin_amdgcn_mfma_f32_16x16x32_bf16(pA, vB1, O[Mt][1], 0, 0, 0);
        }
        #pragma unroll
        for (int Mt = 0; Mt < 2; Mt++){ tc0[Mt] = tn0[Mt]; tc1[Mt] = tn1[Mt]; }
    }
    #pragma unroll
    for (int Mt = 0; Mt < 2; Mt++)
        #pragma unroll
        for (int r = 0; r < 4; r++){
            float l = lsum[Mt][r];
            #pragma unroll
            for (int off = 1; off <= 8; off <<= 1) l += __shfl_xor(l, off);
            lsum[Mt][r] = l;
        }
    #pragma unroll
    for (int Mt = 0; Mt < 2; Mt++)
        #pragma unroll
        for (int r = 0; r < 4; r++){
            float inv = 1.f/lsum[Mt][r];
            int q = q0 + Mt*16 + lq*4 + r;
            float g0 = bf2f(gb[base + (long)q*32 + lm]);
            float g1 = bf2f(gb[base + (long)q*32 + 16 + lm]);
            u32* dst = (u32*)(obuf + (long)(i*NDIM + q)*128 + h*32);
            dst[lm] = pack2_sw(O[Mt][0][r]*inv*g0, O[Mt][1][r]*inv*g1);
        }
}

__global__ __launch_bounds__(512, 2) void attn_kernel(
    const void* mask, const u16* qb, const u16* kb,
    const u16* vb, const u16* gb, const u16* trib, u16* obuf)
{
    __shared__ u16 kS[256*40];     // 20.0 KB
    __shared__ u16 vS[32*264];     // 16.5 KB
    __shared__ u16 pT[8*32*40];    // 20.0 KB per-wave P buffers
    __shared__ float mrow[256];
    if (mask_is_bf16(mask)) attn_body<true >(mask, qb, kb, vb, gb, trib, obuf, kS, vS, pT, mrow);
    else                    attn_body<false>(mask, qb, kb, vb, gb, trib, obuf, kS, vS, pT, mrow);
}

// ===========================================================================
// Kernel C: output projection + bias + residual. grid 512, 512 threads.
//   Weight staged to LDS once (shared); wS reused as oT for the epilogue.
// ===========================================================================
template<bool BF16>
__device__ __forceinline__ void outproj_body(
    const u16* __restrict__ obuf, const u16* __restrict__ woT,
    const void* __restrict__ obias, const void* __restrict__ zraw,
    void* __restrict__ out,
    u16* __restrict__ wS, float* __restrict__ obS)
{
    int t = threadIdx.x, w = t >> 6, L = t & 63;
    int lm = L & 15, lq = L >> 4;
    if (t < 128) obS[t] = ld1<BF16>(obias, t);
    // stage woT into LDS (uint4 copy): 2048 uint4 = 128 rows x 16 uint4
    #pragma unroll
    for (int n = 0; n < 4; n++){
        int g = t + n*512;
        int row = g >> 4, c0 = (g & 15)*8;
        *(uint4*)&wS[row*136 + c0] = ((const uint4*)woT)[g];
    }
    int pos0 = blockIdx.x*128;
    int r0 = w*16;
    f32x4 zero = {0.f,0.f,0.f,0.f};
    bf16x8 aA[4];
    #pragma unroll
    for (int ks = 0; ks < 4; ks++)
        aA[ks] = *(const bf16x8*)&obuf[((long)(pos0 + r0 + lm))*128 + ks*32 + lq*8];
    __syncthreads();
    f32x4 acc[8];
    #pragma unroll
    for (int n8 = 0; n8 < 8; n8++) acc[n8] = zero;
    #pragma unroll
    for (int ks = 0; ks < 4; ks++){
        bf16x8 bB[8];
        #pragma unroll
        for (int n8 = 0; n8 < 8; n8++)
            bB[n8] = *(const bf16x8*)&wS[(n8*16 + lm)*136 + ks*32 + lq*8];
        #pragma unroll
        for (int n8 = 0; n8 < 8; n8++)
            acc[n8] = __builtin_amdgcn_mfma_f32_16x16x32_bf16(aA[ks], bB[n8], acc[n8], 0, 0, 0);
    }
    __syncthreads();   // all wS B-frag reads done -> reuse as oT
    u16* oT = wS;
    #pragma unroll
    for (int n8 = 0; n8 < 8; n8++)
        #pragma unroll
        for (int r = 0; r < 4; r++)
            oT[(r0 + lq*4 + r)*136 + n8*16 + lm] = f2bf(acc[n8][r]);
    __syncthreads();
    if (BF16){
        const uint4* zp = (const uint4*)((const u16*)zraw + (long)pos0*128);
        uint4* op = (uint4*)((u16*)out + (long)pos0*128);
        #pragma unroll
        for (int n = 0; n < 4; n++){
            int g = t + n*512;
            int row = g >> 4, c0 = (g & 15)*8;
            uint4 ov = *(const uint4*)&oT[row*136 + c0];
            uint4 zv = zp[g];
            u16 oe[8], ze[8]; unpack16(ov, oe); unpack16(zv, ze);
            float v[8];
            #pragma unroll
            for (int j = 0; j < 8; j++) v[j] = bf2f(oe[j]) + obS[c0 + j] + bf2f(ze[j]);
            uint4 res;
            res.x = pack2(v[0], v[1]); res.y = pack2(v[2], v[3]);
            res.z = pack2(v[4], v[5]); res.w = pack2(v[6], v[7]);
            op[g] = res;
        }
    } else {
        const float4* zp = (const float4*)((const float*)zraw + (long)pos0*128);
        float4* op = (float4*)((float*)out + (long)pos0*128);
        #pragma unroll
        for (int n = 0; n < 4; n++){
            int g = t + n*512;
            int row = g >> 4, c0 = (g & 15)*8;
            uint4 ov = *(const uint4*)&oT[row*136 + c0];
            u16 oe[8]; unpack16(ov, oe);
            float4 z0 = zp[2*g], z1 = zp[2*g + 1];
            float4 r0v, r1v;
            r0v.x = bf2f(oe[0]) + obS[c0+0] + z0.x;
            r0v.y = bf2f(oe[1]) + obS[c0+1] + z0.y;
            r0v.z = bf2f(oe[2]) + obS[c0+2] + z0.z;
            r0v.w = bf2f(oe[3]) + obS[c0+3] + z0.w;
            r1v.x = bf2f(oe[4]) + obS[c0+4] + z1.x;
            r1v.y = bf2f(oe[5]) + obS[c0+5] + z1.y;
            r1v.z = bf2f(oe[6]) + obS[c0+6] + z1.z;
            r1v.w = bf2f(oe[7]) + obS[c0+7] + z1.w;
            op[2*g] = r0v; op[2*g + 1] = r1v;
        }
    }
}

__global__ __launch_bounds__(512, 2) void outproj_kernel(
    const void* mask, const u16* obuf, const u16* woT,
    const void* obias, const void* zraw, void* out)
{
    __shared__ u16 wS[128*136];
    __shared__ float obS[128];
    if (mask_is_bf16(mask)) outproj_body<true >(obuf, woT, obias, zraw, out, wS, obS);
    else                    outproj_body<false>(obuf, woT, obias, zraw, out, wS, obS);
}

// ===========================================================================
// FALLBACK PATH (round-4, proven at ws >= 17.8 MB) — unchanged kernels
// ===========================================================================
template<bool BF16>
__global__ __launch_bounds__(256) void ln_tri_kernel(
    const void* __restrict__ zraw, const void* __restrict__ mask,
    const void* __restrict__ lnw, const void* __restrict__ lnb,
    const void* __restrict__ wb, u16* __restrict__ trib)
{
    if (mask_is_bf16(mask) != BF16) return;
    int wave = threadIdx.x >> 6;
    int lane = threadIdx.x & 63;
    int pos = blockIdx.x * 4 + wave;
    float2 f = ld2f<BF16>(zraw, (long)pos*64 + lane);
    float x0 = f.x, x1 = f.y;
    float s = x0 + x1, ss = x0*x0 + x1*x1;
    #pragma unroll
    for (int off = 32; off; off >>= 1){ s += __shfl_xor(s, off); ss += __shfl_xor(ss, off); }
    float mean = s * (1.0f/128.0f);
    float var  = ss * (1.0f/128.0f) - mean*mean;
    float rstd = rsqrtf(var + 1e-5f);
    int d0 = lane*2;
    float y0 = (x0 - mean)*rstd*ld1<BF16>(lnw, d0)   + ld1<BF16>(lnb, d0);
    float y1 = (x1 - mean)*rstd*ld1<BF16>(lnw, d0+1) + ld1<BF16>(lnb, d0+1);
    int i = pos >> 8, j = pos & 255;
    #pragma unroll
    for (int hh = 0; hh < 4; hh++){
        float tp = y0*ld1<BF16>(wb, d0*4 + hh) + y1*ld1<BF16>(wb, (d0+1)*4 + hh);
        #pragma unroll
        for (int off = 32; off; off >>= 1) tp += __shfl_xor(tp, off);
        if (lane == 0) trib[((long)(hh*NDIM + i))*NDIM + j] = f2bf(tp);
    }
}

template<bool BF16>
__global__ __launch_bounds__(256, 2) void attn_mfma_kernel(
    const void* __restrict__ zraw, const void* __restrict__ mask,
    const void* __restrict__ lnw, const void* __restrict__ lnb,
    const void* __restrict__ wq, const void* __restrict__ wk,
    const void* __restrict__ wv, const void* __restrict__ wg,
    const void* __restrict__ bg, const u16* __restrict__ trib,
    u16* __restrict__ obuf)
{
    if (mask_is_bf16(mask) != BF16) return;
    __shared__ u16 wT[32*136];
    __shared__ u16 kS[256*40];
    __shared__ u16 vT[32*264];
    __shared__ u16 pT[4*64*40];
    __shared__ float mrow[256];
    __shared__ float lnS[128], lbS[128];

    int i = blockIdx.x >> 2, h = blockIdx.x & 3;
    int t = threadIdx.x, w = t >> 6, L = t & 63;
    int lm = L & 15, lq = L >> 4;
    mrow[t] = 1e9f*(ld1<BF16>(mask, i*NDIM + t) - 1.0f);
    if (t < 128) lnS[t] = ld1<BF16>(lnw, t);
    else         lbS[t-128] = ld1<BF16>(lnb, t-128);
    __syncthreads();

    int q0 = w*64;
    float zf[4][4][8];
    float s[4] = {0,0,0,0}, ss[4] = {0,0,0,0};
    #pragma unroll
    for (int Mt = 0; Mt < 4; Mt++){
        long row = (long)(i*NDIM + q0 + Mt*16 + lm);
        #pragma unroll
        for (int ks = 0; ks < 4; ks++){
            load8f<BF16>(zraw, row*128 + ks*32 + lq*8, zf[Mt][ks]);
            #pragma unroll
            for (int j = 0; j < 8; j++){ float x = zf[Mt][ks][j]; s[Mt] += x; ss[Mt] += x*x; }
        }
    }
    #pragma unroll
    for (int Mt = 0; Mt < 4; Mt++){
        s[Mt]  += __shfl_xor(s[Mt], 16);  s[Mt]  += __shfl_xor(s[Mt], 32);
        ss[Mt] += __shfl_xor(ss[Mt], 16); ss[Mt] += __shfl_xor(ss[Mt], 32);
    }
    bf16x8 zA[4][4];
    #pragma unroll
    for (int Mt = 0; Mt < 4; Mt++){
        float mean = s[Mt]*(1.f/128.f);
        float var  = ss[Mt]*(1.f/128.f) - mean*mean;
        float rstd = rsqrtf(var + 1e-5f);
        #pragma unroll
        for (int ks = 0; ks < 4; ks++){
            float tmp[8];
            #pragma unroll
            for (int j = 0; j < 8; j++){
                int col = ks*32 + lq*8 + j;
                tmp[j] = (zf[Mt][ks][j] - mean)*rstd*lnS[col] + lbS[col];
            }
            zA[Mt][ks] = pack8(tmp);
        }
    }
    u16* myp = pT + w*2560;
    f32x4 zero = {0.f, 0.f, 0.f, 0.f};
    auto stageW = [&](const void* W){
        for (int idx = t; idx < 4096; idx += 256){
            int c = idx >> 7, d = idx & 127;
            wT[c*136 + d] = f2bf(ld1<BF16>(W, (long)(d*4 + h)*32 + c));
        }
    };
    auto projA = [&](f32x4 (&acc)[4][2]){
        bf16x8 bB[2][4];
        #pragma unroll
        for (int Nt = 0; Nt < 2; Nt++)
            #pragma unroll
            for (int ks = 0; ks < 4; ks++)
                bB[Nt][ks] = *(const bf16x8*)&wT[(Nt*16 + lm)*136 + ks*32 + lq*8];
        #pragma unroll
        for (int Mt = 0; Mt < 4; Mt++)
            #pragma unroll
            for (int Nt = 0; Nt < 2; Nt++){
                f32x4 a = zero;
                #pragma unroll
                for (int ks = 0; ks < 4; ks++)
                    a = __builtin_amdgcn_mfma_f32_16x16x32_bf16(zA[Mt][ks], bB[Nt][ks], a, 0, 0, 0);
                acc[Mt][Nt] = a;
            }
    };
    f32x4 acc[4][2];
    stageW(wq); __syncthreads();
    projA(acc);
    #pragma unroll
    for (int Mt = 0; Mt < 4; Mt++)
        #pragma unroll
        for (int Nt = 0; Nt < 2; Nt++)
            #pragma unroll
            for (int r = 0; r < 4; r++)
                myp[(Mt*16 + lq*4 + r)*40 + Nt*16 + lm] = f2bf(acc[Mt][Nt][r]*QK_SCALE);
    bf16x8 qA[4];
    #pragma unroll
    for (int Mt = 0; Mt < 4; Mt++)
        qA[Mt] = *(const bf16x8*)&myp[(Mt*16 + lm)*40 + lq*8];
    __syncthreads();
    stageW(wk); __syncthreads();
    projA(acc);
    #pragma unroll
    for (int Mt = 0; Mt < 4; Mt++)
        #pragma unroll
        for (int Nt = 0; Nt < 2; Nt++)
            #pragma unroll
            for (int r = 0; r < 4; r++)
                kS[(q0 + Mt*16 + lq*4 + r)*40 + Nt*16 + lm] = f2bf(acc[Mt][Nt][r]);
    __syncthreads();
    stageW(wv); __syncthreads();
    projA(acc);
    #pragma unroll
    for (int Mt = 0; Mt < 4; Mt++)
        #pragma unroll
        for (int Nt = 0; Nt < 2; Nt++)
            #pragma unroll
            for (int r = 0; r < 4; r++)
                vT[(Nt*16 + lm)*264 + q0 + Mt*16 + lq*4 + r] = f2bf(acc[Mt][Nt][r]);
    __syncthreads();
    stageW(wg); __syncthreads();
    f32x4 gv[4][2];
    projA(gv);
    float bgv0 = ld1<BF16>(bg, h*32 + lm), bgv1 = ld1<BF16>(bg, h*32 + 16 + lm);
    #pragma unroll
    for (int Mt = 0; Mt < 4; Mt++)
        #pragma unroll
        for (int r = 0; r < 4; r++){
            gv[Mt][0][r] = 1.f/(1.f + __expf(-(gv[Mt][0][r] + bgv0)));
            gv[Mt][1][r] = 1.f/(1.f + __expf(-(gv[Mt][1][r] + bgv1)));
        }
    __syncthreads();
    float mS[4][4], lS[4][4];
    f32x4 O[4][2];
    #pragma unroll
    for (int Mt = 0; Mt < 4; Mt++){
        #pragma unroll
        for (int r = 0; r < 4; r++){ mS[Mt][r] = -3e38f; lS[Mt][r] = 0.f; }
        O[Mt][0] = zero; O[Mt][1] = zero;
    }
    const u16* trb = trib + ((long)(h*NDIM + q0))*NDIM;
    for (int kt = 0; kt < 8; kt++){
        bf16x8 kB0 = *(const bf16x8*)&kS[(kt*32 + lm)*40 + lq*8];
        bf16x8 kB1 = *(const bf16x8*)&kS[(kt*32 + 16 + lm)*40 + lq*8];
        f32x4 S[4][2];
        #pragma unroll
        for (int Mt = 0; Mt < 4; Mt++){
            S[Mt][0] = __builtin_amdgcn_mfma_f32_16x16x32_bf16(qA[Mt], kB0, zero, 0, 0, 0);
            S[Mt][1] = __builtin_amdgcn_mfma_f32_16x16x32_bf16(qA[Mt], kB1, zero, 0, 0, 0);
        }
        int k0 = kt*32 + lm;
        float mb0 = mrow[k0], mb1 = mrow[k0 + 16];
        #pragma unroll
        for (int Mt = 0; Mt < 4; Mt++){
            #pragma unroll
            for (int r = 0; r < 4; r++){
                int qrow = Mt*16 + lq*4 + r;
                float x0 = S[Mt][0][r] + mb0 + bf2f(trb[(long)qrow*NDIM + k0]);
                float x1 = S[Mt][1][r] + mb1 + bf2f(trb[(long)qrow*NDIM + k0 + 16]);
                float mx = fmaxf(x0, x1);
                #pragma unroll
                for (int off = 1; off <= 8; off <<= 1) mx = fmaxf(mx, __shfl_xor(mx, off));
                float mnew = fmaxf(mS[Mt][r], mx);
                float al = __expf(mS[Mt][r] - mnew);
                float p0 = __expf(x0 - mnew), p1 = __expf(x1 - mnew);
                float rs = p0 + p1;
                #pragma unroll
                for (int off = 1; off <= 8; off <<= 1) rs += __shfl_xor(rs, off);
                lS[Mt][r] = lS[Mt][r]*al + rs;
                mS[Mt][r] = mnew;
                O[Mt][0][r] *= al; O[Mt][1][r] *= al;
                myp[qrow*40 + lm]      = f2bf(p0);
                myp[qrow*40 + 16 + lm] = f2bf(p1);
            }
        }
        bf16x8 vB0 = *(const bf16x8*)&vT[lm*264 + kt*32 + lq*8];
        bf16x8 vB1 = *(const bf16x8*)&vT[(16 + lm)*264 + kt*32 + lq*8];
        #pragma unroll
        for (int Mt = 0; Mt < 4; Mt++){
            bf16x8 pA = *(const bf16x8*)&myp[(Mt*16 + lm)*40 + lq*8];
            O[Mt][0] = __builtin_amdgcn_mfma_f32_16x16x32_bf16(pA, vB0, O[Mt][0], 0, 0, 0);
            O[Mt][1] = __builtin_amdgcn_mfma_f32_16x16x32_bf16(pA, vB1, O[Mt][1], 0, 0, 0);
        }
    }
    #pragma unroll
    for (int Mt = 0; Mt < 4; Mt++)
        #pragma unroll
        for (int r = 0; r < 4; r++){
            float inv = 1.0f/lS[Mt][r];
            int q = q0 + Mt*16 + lq*4 + r;
            long base = ((long)(i*NDIM + q))*128 + h*32;
            obuf[base + lm]      = f2bf(O[Mt][0][r]*inv*gv[Mt][0][r]);
            obuf[base + 16 + lm] = f2bf(O[Mt][1][r]*inv*gv[Mt][1][r]);
        }
}

// ---------------------------------------------------------------------------
extern "C" void kernel_launch(void* const* d_in, const int* in_sizes, int n_in,
                              void* d_out, int out_size, void* d_ws, size_t ws_size,
                              hipStream_t stream)
{
    const void* zraw = d_in[0];
    const void* mask = d_in[1];
    const void* lnw  = d_in[2];
    const void* lnb  = d_in[3];
    const void* wb   = d_in[4];
    const void* wq   = d_in[5];
    const void* wk   = d_in[6];
    const void* wv   = d_in[7];
    const void* wg   = d_in[8];
    const void* bg   = d_in[9];
    const void* wo   = d_in[10];
    const void* obias= d_in[11];

    const size_t KB = 1024;
    const size_t MB = 1024*1024;
    u16* trib = (u16*)d_ws;                               // 512 KB @ 0
    u16* wT4  = (u16*)((char*)d_ws + 512*KB);             // 128 KB
    u16* woP  = (u16*)((char*)d_ws + 640*KB);             // 32 KB
    u16* woL  = (u16*)((char*)d_ws + 672*KB);             // 32 KB
    u16* wbT  = (u16*)((char*)d_ws + 704*KB);             // 4 KB
    size_t need_big = 81*MB;
    bool big = ws_size >= need_big;

    prep_kernel<<<dim3(128), 256, 0, stream>>>(mask, wq, wk, wv, wg, wb, wo,
                                               wT4, wbT, woP, woL);
    if (big){
        u16* qb   = (u16*)((char*)d_ws + 1*MB);
        u16* kb   = (u16*)((char*)d_ws + 17*MB);
        u16* vb   = (u16*)((char*)d_ws + 33*MB);
        u16* gb   = (u16*)((char*)d_ws + 49*MB);
        u16* obuf = (u16*)((char*)d_ws + 65*MB);
        proj_kernel<<<dim3(512), 512, 0, stream>>>(
            zraw, mask, lnw, lnb, wT4, wbT, bg, trib, qb, kb, vb, gb);
        attn_kernel<<<dim3(1024), 512, 0, stream>>>(mask, qb, kb, vb, gb, trib, obuf);
        outproj_kernel<<<dim3(512), 512, 0, stream>>>(mask, obuf, woP, obias, zraw, d_out);
    } else {
        u16* obuf = (u16*)((char*)d_ws + 1*MB);
        ln_tri_kernel<true ><<<dim3(NDIM*NDIM/4), 256, 0, stream>>>(zraw, mask, lnw, lnb, wb, trib);
        ln_tri_kernel<false><<<dim3(NDIM*NDIM/4), 256, 0, stream>>>(zraw, mask, lnw, lnb, wb, trib);
        attn_mfma_kernel<true ><<<dim3(NDIM*HDIM), 256, 0, stream>>>(
            zraw, mask, lnw, lnb, wq, wk, wv, wg, bg, trib, obuf);
        attn_mfma_kernel<false><<<dim3(NDIM*HDIM), 256, 0, stream>>>(
            zraw, mask, lnw, lnb, wq, wk, wv, wg, bg, trib, obuf);
        outproj_kernel<<<dim3(512), 512, 0, stream>>>(mask, obuf, woL, obias, zraw, d_out);
    }
}